// Round 7
// baseline (111.387 us; speedup 1.0000x reference)
//
#include <hip/hip_runtime.h>

#define BB 16
#define LL 1444
#define DD 128
#define CC 21
#define CH 38   // chunk length
#define NK 38   // number of chunks; CH*NK == LL
#define RH 19   // row-half of a chunk
#define KK (CH + 2*CC)   // 80: [v(38) | pre0(21) | tot(21)]
#define GSTRIDE (KK * 40)  // per-chunk G floats: [k][half][20]

#define CS_ELEMS ((size_t)BB*NK*CC*DD)
#define TOT_ELEMS ((size_t)BB*CC*DD)

#define ASG __attribute__((address_space(1)))
#define ASL __attribute__((address_space(3)))

static __device__ __forceinline__ void gll16(const float* g, float* l) {
  __builtin_amdgcn_global_load_lds((const ASG void*)g, (ASL void*)l, 16, 0, 0);
}
static __device__ __forceinline__ void gll4(const float* g, float* l) {
  __builtin_amdgcn_global_load_lds((const ASG void*)g, (ASL void*)l, 4, 0, 0);
}

// K1: per-chunk class sums + src passthrough + G-matrix build.
// G[t][k] (k<38: strictly-lower Q gather + Ss diag; 38..58: Q[ct][:]; 59..79:
// P[:][ct]) depends only on idx/P, so it's built here, stored [k][half][20]
// (80B groups, 16B-aligned) for k4's scalar s_load path.
__global__ __launch_bounds__(256) void k1_chunk_sums(
    const float* __restrict__ src, const int* __restrict__ idx,
    const float* __restrict__ P, float* __restrict__ cs,
    float* __restrict__ Gws, float* __restrict__ src_copy)
{
  __shared__ __align__(16) float Vs[CH][DD];   // 19456 B
  int tid = threadIdx.x;
  int w = tid >> 6, lane = tid & 63;
  int b = blockIdx.x / NK, kc = blockIdx.x % NK;
  int i0 = kc * CH;
  const float* sc = src + (size_t)(b * LL + i0) * DD;

  for (int i = w; i < 19; i += 4)                  // async stage, 19 x 1024B
    gll16(sc + i * 256 + lane * 4, &Vs[0][0] + i * 256);

  // G build overlaps the async staging latency
  const int* gidx = idx + b * LL + i0;
  float* Gc = Gws + (size_t)blockIdx.x * GSTRIDE;
  for (int e = tid; e < GSTRIDE; e += 256) {
    int k = e / 40;
    int r = e - k * 40;
    int half = r / 20, j = r - half * 20;
    int t = half * RH + j;
    float val = 0.f;
    if (j < RH) {
      int ct = gidx[t];
      if (k < CH) {
        if (k < t) { int ck = gidx[k]; val = P[ct * CC + ck] - P[ck * CC + ct]; }
        else if (k == t) val = (ct != 0 ? 1.0f : 0.0f) - P[ct * CC + ct];
      } else if (k < CH + CC) {
        int c = k - CH; val = P[ct * CC + c] - P[c * CC + ct];
      } else {
        int c = k - CH - CC; val = P[c * CC + ct];
      }
    }
    Gc[e] = val;
  }
  __syncthreads();

  int d = tid & 127;
  int c0 = (tid >> 7) * 10;                        // class groups 0..10 / 10..20
  float acc[11];
#pragma unroll
  for (int j = 0; j < 11; ++j) acc[j] = 0.f;

#pragma unroll
  for (int t = 0; t < CH; ++t) {
    int ct = gidx[t];
    float v = Vs[t][d];
#pragma unroll
    for (int j = 0; j < 11; ++j) {
      float m = (ct == c0 + j) ? 1.0f : 0.0f;      // scalar cmp+cselect
      acc[j] += m * v;
    }
  }

  float* co = cs + ((size_t)(b * NK + kc) * CC) * DD + d;
#pragma unroll
  for (int j = 0; j < 11; ++j) co[(c0 + j) * DD] = acc[j];

  const float4* v4 = (const float4*)&Vs[0][0];
  float4* o4 = (float4*)(src_copy + (size_t)(b * LL + i0) * DD);
  for (int i = tid; i < CH * DD / 4; i += 256) o4[i] = v4[i];
}

// K2: exclusive scan over NK chunks per (b,c); two 19-deep batches (no spill).
__global__ __launch_bounds__(128) void k2_scan(
    float* __restrict__ cs, float* __restrict__ tot)
{
  int b = blockIdx.x / CC, c = blockIdx.x % CC;
  int d = threadIdx.x;
  float* base = cs + ((size_t)(b * NK) * CC + c) * DD + d;
  const int S = CC * DD;
  float a[RH];
  float run = 0.f;
#pragma unroll
  for (int i = 0; i < RH; ++i) a[i] = base[(size_t)i * S];
#pragma unroll
  for (int i = 0; i < RH; ++i) { float t = a[i]; base[(size_t)i * S] = run; run += t; }
#pragma unroll
  for (int i = 0; i < RH; ++i) a[i] = base[(size_t)(RH + i) * S];
#pragma unroll
  for (int i = 0; i < RH; ++i) { float t = a[i]; base[(size_t)(RH + i) * S] = run; run += t; }
  tot[((size_t)(b * CC + c)) * DD + d] = run;
}

// K4: out(t,d) = sum_k G[t][k]*X[k][d]. X in LDS (ds_read_b64/thread), G via
// wave-uniform s_load into SGPRs (v_fmac v,s,v) — removes the R6 LDS-broadcast
// bottleneck (5x ds_read_b128 per k-iter). 128 thr = 2 waves = 2 row-halves;
// each thread owns a d-pair; acc = 19 float2 = 38 VGPR.
__global__ __launch_bounds__(128) void k4_fused(
    const float* __restrict__ src, const float* __restrict__ cs,
    const float* __restrict__ tot, const float* __restrict__ Gws,
    float* __restrict__ out)
{
  __shared__ __align__(16) float X[KK][DD];    // 40960 B
  int tid = threadIdx.x;
  int w = tid >> 6, lane = tid & 63;
  int b = blockIdx.x / NK, kc = blockIdx.x % NK;
  int i0 = kc * CH;

  const float* sc = src + (size_t)(b * LL + i0) * DD;
  const float* pc = cs + ((size_t)(b * NK + kc) * CC) * DD;
  const float* tb = tot + (size_t)b * CC * DD;
  float* xf = &X[0][0];

  // async staging: v 19456B, pre0 10752B, tot 10752B
  for (int i = w; i < 19; i += 2) gll16(sc + i * 256 + lane * 4, xf + i * 256);
  for (int i = w; i < 10; i += 2) gll16(pc + i * 256 + lane * 4, xf + CH * DD + i * 256);
  for (int i = w; i < 10; i += 2) gll16(tb + i * 256 + lane * 4, xf + (CH + CC) * DD + i * 256);
  if (w == 0) {
    gll4(pc + 2560 + lane, xf + CH * DD + 2560 + lane);
    gll4(pc + 2624 + lane, xf + CH * DD + 2624 + lane);
  } else {
    gll4(tb + 2560 + lane, xf + (CH + CC) * DD + 2560 + lane);
    gll4(tb + 2624 + lane, xf + (CH + CC) * DD + 2624 + lane);
  }
  __syncthreads();

  int rw = __builtin_amdgcn_readfirstlane(w);        // row-half (wave-uniform)
  const float* Gc = Gws + (size_t)blockIdx.x * GSTRIDE + rw * 20;
  const float2* Xp = (const float2*)xf;

  float2 acc[RH];
#pragma unroll
  for (int j = 0; j < RH; ++j) acc[j] = make_float2(0.f, 0.f);

  // rows t<19 have G[t][k]=0 for k in [19,38) — skip that block for wave 0
  int kend1 = __builtin_amdgcn_readfirstlane(rw ? CH : RH);
#pragma unroll 2
  for (int k = 0; k < kend1; ++k) {
    const float* g = Gc + k * 40;                    // uniform -> s_load
    float2 x = Xp[k * 64 + lane];
#pragma unroll
    for (int j = 0; j < RH; ++j) {
      acc[j].x += g[j] * x.x;
      acc[j].y += g[j] * x.y;
    }
  }
#pragma unroll 2
  for (int k = CH; k < KK; ++k) {
    const float* g = Gc + k * 40;
    float2 x = Xp[k * 64 + lane];
#pragma unroll
    for (int j = 0; j < RH; ++j) {
      acc[j].x += g[j] * x.x;
      acc[j].y += g[j] * x.y;
    }
  }

  float2* op = (float2*)(out + (size_t)(b * LL + i0 + rw * RH) * DD) + lane;
#pragma unroll
  for (int j = 0; j < RH; ++j) op[j * 64] = acc[j];
}

extern "C" void kernel_launch(void* const* d_in, const int* in_sizes, int n_in,
                              void* d_out, int out_size, void* d_ws, size_t ws_size,
                              hipStream_t stream) {
  const float* P   = (const float*)d_in[0];   // cls_r_prob (C*C)
  const float* src = (const float*)d_in[1];   // source (B*L*D)
  const int*   idx = (const int*)d_in[2];     // class_idx (B*L)

  float* out_fused = (float*)d_out;                      // first B*L*D
  float* out_src   = out_fused + (size_t)BB * LL * DD;   // second B*L*D

  float* cs  = (float*)d_ws;            // [B][NK][C][D]
  float* tot = cs + CS_ELEMS;           // [B][C][D]
  float* Gws = tot + TOT_ELEMS;         // [608][80][2][20]

  k1_chunk_sums<<<BB * NK, 256, 0, stream>>>(src, idx, P, cs, Gws, out_src);
  k2_scan<<<BB * CC, 128, 0, stream>>>(cs, tot);
  k4_fused<<<BB * NK, 128, 0, stream>>>(src, cs, tot, Gws, out_fused);
}

// Round 8
// 101.595 us; speedup vs baseline: 1.0964x; 1.0964x over previous
//
#include <hip/hip_runtime.h>

#define BB 16
#define LL 1444
#define DD 128
#define CC 21
#define CH 38   // chunk length
#define NK 38   // number of chunks; CH*NK == LL
#define RH 19   // row-half of a chunk
#define KK (CH + 2*CC)   // 80: [v(38) | pre0(21) | tot(21)]

#define CS_ELEMS ((size_t)BB*NK*CC*DD)

#define ASG __attribute__((address_space(1)))
#define ASL __attribute__((address_space(3)))

static __device__ __forceinline__ void gll16(const float* g, float* l) {
  __builtin_amdgcn_global_load_lds((const ASG void*)g, (ASL void*)l, 16, 0, 0);
}
static __device__ __forceinline__ void gll4(const float* g, float* l) {
  __builtin_amdgcn_global_load_lds((const ASG void*)g, (ASL void*)l, 4, 0, 0);
}

// K1: per-chunk per-class sums + src passthrough. Branch-free: scalar-select
// mask FMAs (class index is a uniform s_load). 256 threads: d x 2 class-groups.
__global__ __launch_bounds__(256) void k1_chunk_sums(
    const float* __restrict__ src, const int* __restrict__ idx,
    float* __restrict__ cs, float* __restrict__ src_copy)
{
  __shared__ __align__(16) float Vs[CH][DD];   // 19456 B
  int tid = threadIdx.x;
  int w = tid >> 6, lane = tid & 63;
  int b = blockIdx.x / NK, kc = blockIdx.x % NK;
  int i0 = kc * CH;
  const float* sc = src + (size_t)(b * LL + i0) * DD;

  for (int i = w; i < 19; i += 4)                  // 19 x 1024B async issues
    gll16(sc + i * 256 + lane * 4, &Vs[0][0] + i * 256);
  __syncthreads();

  const int* gidx = idx + b * LL + i0;             // uniform address -> s_load
  int d = tid & 127;
  int c0 = (tid >> 7) * 10;                        // groups c=0..10 / c=10..20
  float acc[11];
#pragma unroll
  for (int j = 0; j < 11; ++j) acc[j] = 0.f;

#pragma unroll
  for (int t = 0; t < CH; ++t) {
    int ct = gidx[t];
    float v = Vs[t][d];
#pragma unroll
    for (int j = 0; j < 11; ++j) {
      float m = (ct == c0 + j) ? 1.0f : 0.0f;      // scalar cmp+cselect
      acc[j] += m * v;
    }
  }

  float* co = cs + ((size_t)(b * NK + kc) * CC) * DD + d;
#pragma unroll
  for (int j = 0; j < 11; ++j) co[(c0 + j) * DD] = acc[j];

  const float4* v4 = (const float4*)&Vs[0][0];
  float4* o4 = (float4*)(src_copy + (size_t)(b * LL + i0) * DD);
  for (int i = tid; i < CH * DD / 4; i += 256) o4[i] = v4[i];
}

// K2: exclusive scan over NK chunks per (b,c); two 19-deep batches (no spill).
__global__ __launch_bounds__(128) void k2_scan(
    float* __restrict__ cs, float* __restrict__ tot)
{
  int b = blockIdx.x / CC, c = blockIdx.x % CC;
  int d = threadIdx.x;
  float* base = cs + ((size_t)(b * NK) * CC + c) * DD + d;
  const int S = CC * DD;
  float a[RH];
  float run = 0.f;
#pragma unroll
  for (int i = 0; i < RH; ++i) a[i] = base[(size_t)i * S];
#pragma unroll
  for (int i = 0; i < RH; ++i) { float t = a[i]; base[(size_t)i * S] = run; run += t; }
#pragma unroll
  for (int i = 0; i < RH; ++i) a[i] = base[(size_t)(RH + i) * S];
#pragma unroll
  for (int i = 0; i < RH; ++i) { float t = a[i]; base[(size_t)(RH + i) * S] = run; run += t; }
  tot[((size_t)(b * CC + c)) * DD + d] = run;
}

// K4: one dense fp32 "GEMM" per chunk: out(t,d) = sum_k G[t][k] * X[k][d].
// X = [v | pre0 | tot] async-staged to LDS; G built in parallel from P/idx.
#define GEMM_BODY(kv)                                                   \
  {                                                                     \
    float x = X[(kv)][d];                                               \
    const float4* gp = (const float4*)(Gh + (kv) * 20);                 \
    float4 g0 = gp[0], g1 = gp[1], g2 = gp[2], g3 = gp[3], g4 = gp[4];  \
    acc[0]  += g0.x * x; acc[1]  += g0.y * x; acc[2]  += g0.z * x;      \
    acc[3]  += g0.w * x; acc[4]  += g1.x * x; acc[5]  += g1.y * x;      \
    acc[6]  += g1.z * x; acc[7]  += g1.w * x; acc[8]  += g2.x * x;      \
    acc[9]  += g2.y * x; acc[10] += g2.z * x; acc[11] += g2.w * x;      \
    acc[12] += g3.x * x; acc[13] += g3.y * x; acc[14] += g3.z * x;      \
    acc[15] += g3.w * x; acc[16] += g4.x * x; acc[17] += g4.y * x;      \
    acc[18] += g4.z * x;                                                \
  }

__global__ __launch_bounds__(256) void k4_fused(
    const float* __restrict__ src, const int* __restrict__ idx,
    const float* __restrict__ P, const float* __restrict__ cs,
    const float* __restrict__ tot, float* __restrict__ out)
{
  __shared__ __align__(16) float X[KK][DD];    // 40960 B
  __shared__ __align__(16) float GA[KK][20];   // rows t=0..18 (+pad)
  __shared__ __align__(16) float GB[KK][20];   // rows t=19..37 (+pad)

  int tid = threadIdx.x;
  int w = tid >> 6, lane = tid & 63;
  int b = blockIdx.x / NK, kc = blockIdx.x % NK;
  int i0 = kc * CH;

  const float* sc = src + (size_t)(b * LL + i0) * DD;
  const float* pc = cs + ((size_t)(b * NK + kc) * CC) * DD;
  const float* tb = tot + (size_t)b * CC * DD;
  float* xf = &X[0][0];

  for (int i = w; i < 19; i += 4) gll16(sc + i * 256 + lane * 4, xf + i * 256);
  for (int i = w; i < 10; i += 4) gll16(pc + i * 256 + lane * 4, xf + CH * DD + i * 256);
  for (int i = w; i < 10; i += 4) gll16(tb + i * 256 + lane * 4, xf + (CH + CC) * DD + i * 256);
  if (w < 2) gll4(pc + 2560 + w * 64 + lane, xf + CH * DD + 2560 + w * 64);
  else       gll4(tb + 2560 + (w - 2) * 64 + lane, xf + (CH + CC) * DD + 2560 + (w - 2) * 64);

  // G build overlaps staging
  const int* gidx = idx + b * LL + i0;
  for (int e = tid; e < 2 * KK * 20; e += 256) {
    int h = e / (KK * 20);
    int rem = e - h * (KK * 20);
    int k = rem / 20, j = rem - k * 20;
    int t = h * RH + j;
    float val = 0.f;
    if (j < RH) {
      int ct = gidx[t];
      if (k < CH) {
        if (k < t) { int ck = gidx[k]; val = P[ct * CC + ck] - P[ck * CC + ct]; }
        else if (k == t) val = (ct != 0 ? 1.0f : 0.0f) - P[ct * CC + ct];
      } else if (k < CH + CC) {
        int c = k - CH; val = P[ct * CC + c] - P[c * CC + ct];
      } else {
        int c = k - CH - CC; val = P[c * CC + ct];
      }
    }
    (h ? &GB[0][0] : &GA[0][0])[k * 20 + j] = val;
  }
  __syncthreads();

  int rw = __builtin_amdgcn_readfirstlane(w >> 1);   // row-half (uniform)
  int dh = w & 1;
  int d = dh * 64 + lane;
  const float* Gh = rw ? &GB[0][0] : &GA[0][0];

  float acc[RH];
#pragma unroll
  for (int j = 0; j < RH; ++j) acc[j] = 0.f;

  int kend1 = __builtin_amdgcn_readfirstlane(rw ? CH : RH);
  for (int k = 0; k < kend1; ++k) GEMM_BODY(k)
  for (int k = CH; k < KK; ++k)   GEMM_BODY(k)

  float* op = out + (size_t)(b * LL + i0 + rw * RH) * DD + d;
#pragma unroll
  for (int j = 0; j < RH; ++j) op[(size_t)j * DD] = acc[j];
}

extern "C" void kernel_launch(void* const* d_in, const int* in_sizes, int n_in,
                              void* d_out, int out_size, void* d_ws, size_t ws_size,
                              hipStream_t stream) {
  const float* P   = (const float*)d_in[0];   // cls_r_prob (C*C)
  const float* src = (const float*)d_in[1];   // source (B*L*D)
  const int*   idx = (const int*)d_in[2];     // class_idx (B*L)

  float* out_fused = (float*)d_out;                      // first B*L*D
  float* out_src   = out_fused + (size_t)BB * LL * DD;   // second B*L*D

  float* cs  = (float*)d_ws;           // [B][NK][C][D]
  float* tot = cs + CS_ELEMS;          // [B][C][D]

  k1_chunk_sums<<<BB * NK, 256, 0, stream>>>(src, idx, cs, out_src);
  k2_scan<<<BB * CC, 128, 0, stream>>>(cs, tot);
  k4_fused<<<BB * NK, 256, 0, stream>>>(src, idx, P, cs, tot, out_fused);
}